// Round 8
// baseline (4947.023 us; speedup 1.0000x reference)
//
#include <hip/hip_runtime.h>
#include <cstdint>
#include <cstddef>

// Problem constants (match reference)
#define NIT    500
#define GAMMA_ 5.0f
#define CC_    1e-3f
#define KAPPA_ 2.0627128075074256f
#define PEN_   100.0f
#define LR_    0.01f

// d_ws layout: pbuf [128 b][2 dir][4 slot][100] f32 = 409600 B, then flags [256] int
#define PBUF_BYTES (128*2*4*100*4)
#define FLAG_COUNT 256

__device__ __forceinline__ float rdlane(float v, int lane) {
  return __int_as_float(__builtin_amdgcn_readlane(__float_as_int(v), lane));
}

// Wave64 sum via DPP, total broadcast from lane 63. Numerics verified r5/r7.
__device__ __forceinline__ float wred64(float x) {
  int t;
  t = __builtin_amdgcn_update_dpp(0, __float_as_int(x), 0x111, 0xf, 0xf, true); x += __int_as_float(t);
  t = __builtin_amdgcn_update_dpp(0, __float_as_int(x), 0x112, 0xf, 0xf, true); x += __int_as_float(t);
  t = __builtin_amdgcn_update_dpp(0, __float_as_int(x), 0x114, 0xf, 0xf, true); x += __int_as_float(t);
  t = __builtin_amdgcn_update_dpp(0, __float_as_int(x), 0x118, 0xf, 0xf, true); x += __int_as_float(t);
  t = __builtin_amdgcn_update_dpp(0, __float_as_int(x), 0x142, 0xa, 0xf, true); x += __int_as_float(t);
  t = __builtin_amdgcn_update_dpp(0, __float_as_int(x), 0x143, 0xc, 0xf, true); x += __int_as_float(t);
  return rdlane(x, 63);
}

// 256 WGs, one per (b, half): 6 heads x 2 waves. REDUNDANT POST: both waves of a
// head hold w in registers and compute the identical update, so the only tight
// per-iter handshake is the y-half exchange. Ring depths: wbuf 4, pbuf 4, ybuf 2
// (overwrite safety proved from the yf -> post-done gating chain).
__global__ __launch_bounds__(768, 1) void mpo_solver(
    const float* __restrict__ mu, const float* __restrict__ L,
    const float* __restrict__ wprev, const float* __restrict__ climit,
    float* __restrict__ out, float* __restrict__ pbuf, int* __restrict__ flags)
{
  const int tid  = threadIdx.x;
  const int lane = tid & 63;
  const int wave = __builtin_amdgcn_readfirstlane(tid >> 6);  // 0..11
  const int j    = wave >> 1;       // head 0..5
  const int sec  = wave & 1;        // 0 = rows 0-49 ("A", publisher), 1 = rows 50-99 ("B")
  const int bid  = blockIdx.x;
  const int b    = bid & 127;
  const int half = bid >> 7;        // 0: heads 0-5, 1: heads 6-11
  const int h    = half * 6 + j;
  const int bh   = b * 12 + h;

  __shared__ float wbuf[4][6][100];   // ring-4 iterate per head (slot = k & 3 holds w(k))
  __shared__ float ybuf[2][6][100];   // ring-2 y = S w per head (slot = k & 1)
  __shared__ int   yf[2][6];          // yf[sec][j]: y-half of iter k published -> k+1
  __shared__ int   wf[6];             // w(k+1) published in wbuf[(k+1)&3] -> k+1

  const float* Lb = L + (size_t)bh * 10000;

  // ---------- Phase 0: SYRK. Lane owns row r of S = L L^T (fp32, in registers). ----------
  float S[100];
#pragma unroll
  for (int c = 0; c < 100; ++c) S[c] = 0.f;
  const int r = sec * 50 + lane;      // valid row iff lane < 50
  if (lane < 50) {
#pragma unroll 1
    for (int mc = 0; mc < 25; ++mc) {
      float4 lr = *(const float4*)(Lb + r * 100 + mc * 4);
#pragma unroll
      for (int c = 0; c < 100; ++c) {
        const float* Lc = Lb + c * 100 + mc * 4;   // wave-uniform address -> scalar loads
        S[c] = fmaf(lr.x, Lc[0], fmaf(lr.y, Lc[1], fmaf(lr.z, Lc[2], fmaf(lr.w, Lc[3], S[c]))));
      }
    }
  }

  const bool val1 = (lane < 36);
  float mu0 = mu[(size_t)bh * 100 + lane];
  float mu1 = val1 ? mu[(size_t)bh * 100 + 64 + lane] : 0.f;
  float wp0 = wprev[b * 100 + lane];
  float wp1 = val1 ? wprev[b * 100 + 64 + lane] : 0.f;
  float lim = climit[b];

  float w0 = wp0, w1 = wp1;           // BOTH waves carry the iterate in registers

  if (sec == 0) {
    wbuf[0][j][lane] = wp0;
    if (val1) wbuf[0][j][64 + lane] = wp1;
  }
  if (tid < 6) { wf[tid] = 0; yf[0][tid] = 0; yf[1][tid] = 0; }
  __syncthreads();   // only barrier: initial state + flags

  const bool hasNext = (h < 11);
  const bool crossR  = (half == 0) && (j == 5);  // right neighbor (head 6) is cross-WG
  const bool crossL  = (half == 1) && (j == 0);  // left  neighbor (head 5) is cross-WG
  const int  flagPub = crossR ? (b * 2 + 0) : (b * 2 + 1);
  const int  flagCon = crossR ? (b * 2 + 1) : (b * 2 + 0);
  bool dead = false;
  float thp = -3.0e38f;               // previous theta (warm support seed); k=0 -> full

  for (int k = 0; k < NIT; ++k) {
    const int pw = k & 3;             // wbuf/pbuf slot holding w(k)
    const int py = k & 1;             // ybuf slot for iter k

    // ---------- matvec own half from REGISTERS (no wait) ----------
    {
      float a0 = 0.f, a1 = 0.f, a2 = 0.f, a3 = 0.f;
#pragma unroll
      for (int c = 0; c < 64; c += 4) {
        a0 = fmaf(rdlane(w0, c + 0), S[c + 0], a0);
        a1 = fmaf(rdlane(w0, c + 1), S[c + 1], a1);
        a2 = fmaf(rdlane(w0, c + 2), S[c + 2], a2);
        a3 = fmaf(rdlane(w0, c + 3), S[c + 3], a3);
      }
#pragma unroll
      for (int c = 64; c < 100; c += 4) {
        a0 = fmaf(rdlane(w1, c - 64), S[c + 0], a0);
        a1 = fmaf(rdlane(w1, c - 63), S[c + 1], a1);
        a2 = fmaf(rdlane(w1, c - 62), S[c + 2], a2);
        a3 = fmaf(rdlane(w1, c - 61), S[c + 3], a3);
      }
      if (lane < 50) ybuf[py][j][r] = (a0 + a2) + (a1 + a3);
    }
    if (lane == 0)
      __hip_atomic_store(&yf[sec][j], k + 1, __ATOMIC_RELEASE, __HIP_MEMORY_SCOPE_WORKGROUP);

    // ---------- neighbor w(k) loads (overlap their latency with partner wait) ----------
    float wl0, wl1, wn0 = 0.f, wn1 = 0.f;
    if (j == 0) {
      if (half == 0 || k == 0) { wl0 = wp0; wl1 = wp1; }
      else {  // crossL: head 5 from partner WG
        if (!dead &&
            __hip_atomic_load(&flags[flagCon], __ATOMIC_ACQUIRE, __HIP_MEMORY_SCOPE_AGENT) < k) {
          long g = 0;
          while (__hip_atomic_load(&flags[flagCon], __ATOMIC_ACQUIRE, __HIP_MEMORY_SCOPE_AGENT) < k) {
            __builtin_amdgcn_s_sleep(1);
            if (++g > (1L << 20)) { dead = true; break; }
          }
        }
        const float* src = pbuf + ((size_t)flagCon * 4 + pw) * 100;
        wl0 = __hip_atomic_load(&src[lane], __ATOMIC_RELAXED, __HIP_MEMORY_SCOPE_AGENT);
        wl1 = val1 ? __hip_atomic_load(&src[64 + lane], __ATOMIC_RELAXED, __HIP_MEMORY_SCOPE_AGENT) : 0.f;
      }
    } else {
      if (!dead &&
          __hip_atomic_load(&wf[j - 1], __ATOMIC_ACQUIRE, __HIP_MEMORY_SCOPE_WORKGROUP) < k) {
        long g = 0;
        while (__hip_atomic_load(&wf[j - 1], __ATOMIC_ACQUIRE, __HIP_MEMORY_SCOPE_WORKGROUP) < k) {
          __builtin_amdgcn_s_sleep(1);
          if (++g > (1L << 20)) { dead = true; break; }
        }
      }
      wl0 = wbuf[pw][j - 1][lane];
      wl1 = val1 ? wbuf[pw][j - 1][64 + lane] : 0.f;
    }
    if (hasNext) {
      if (j == 5) {  // crossR (half==0): head 6 from partner WG
        if (k == 0) { wn0 = wp0; wn1 = wp1; }
        else {
          if (!dead &&
              __hip_atomic_load(&flags[flagCon], __ATOMIC_ACQUIRE, __HIP_MEMORY_SCOPE_AGENT) < k) {
            long g = 0;
            while (__hip_atomic_load(&flags[flagCon], __ATOMIC_ACQUIRE, __HIP_MEMORY_SCOPE_AGENT) < k) {
              __builtin_amdgcn_s_sleep(1);
              if (++g > (1L << 20)) { dead = true; break; }
            }
          }
          const float* src = pbuf + ((size_t)flagCon * 4 + pw) * 100;
          wn0 = __hip_atomic_load(&src[lane], __ATOMIC_RELAXED, __HIP_MEMORY_SCOPE_AGENT);
          wn1 = val1 ? __hip_atomic_load(&src[64 + lane], __ATOMIC_RELAXED, __HIP_MEMORY_SCOPE_AGENT) : 0.f;
        }
      } else {
        if (!dead &&
            __hip_atomic_load(&wf[j + 1], __ATOMIC_ACQUIRE, __HIP_MEMORY_SCOPE_WORKGROUP) < k) {
          long g = 0;
          while (__hip_atomic_load(&wf[j + 1], __ATOMIC_ACQUIRE, __HIP_MEMORY_SCOPE_WORKGROUP) < k) {
            __builtin_amdgcn_s_sleep(1);
            if (++g > (1L << 20)) { dead = true; break; }
          }
        }
        wn0 = wbuf[pw][j + 1][lane];
        wn1 = val1 ? wbuf[pw][j + 1][64 + lane] : 0.f;
      }
    }

    // ---------- partner y-half (the one tight handshake) ----------
    if (!dead &&
        __hip_atomic_load(&yf[1 - sec][j], __ATOMIC_ACQUIRE, __HIP_MEMORY_SCOPE_WORKGROUP) < k + 1) {
      long g = 0;
      while (__hip_atomic_load(&yf[1 - sec][j], __ATOMIC_ACQUIRE, __HIP_MEMORY_SCOPE_WORKGROUP) < k + 1) {
        __builtin_amdgcn_s_sleep(1);
        if (++g > (1L << 20)) { dead = true; break; }
      }
    }
    float y0 = ybuf[py][j][lane];
    float y1 = val1 ? ybuf[py][j][64 + lane] : 0.f;

    // ---------- post (computed REDUNDANTLY by both waves; bit-identical) ----------
    float ret = wred64(fmaf(mu0, w0, mu1 * w1));
    float s2  = wred64(fmaf(y0, w0, y1 * w1));
    float sigma = sqrtf(s2 + 1e-12f);
    float z     = KAPPA_ * sigma - ret - lim;
    float act   = (z > 0.f) ? 1.f : 0.f;
    float cY    = 2.f * GAMMA_ + act * (PEN_ * KAPPA_ / sigma);
    float cM    = -(1.f + act * PEN_);

    float dw0 = w0 - wl0;
    float g0  = fmaf(cM, mu0, cY * y0) + CC_ * (dw0 * rsqrtf(fmaf(dw0, dw0, 1e-10f)));
    if (hasNext) { float dn0 = wn0 - w0; g0 -= CC_ * (dn0 * rsqrtf(fmaf(dn0, dn0, 1e-10f))); }
    float v0 = fmaf(-LR_, g0, w0);
    float v1 = 0.f;
    if (val1) {
      float dw1 = w1 - wl1;
      float g1  = fmaf(cM, mu1, cY * y1) + CC_ * (dw1 * rsqrtf(fmaf(dw1, dw1, 1e-10f)));
      if (hasNext) { float dn1 = wn1 - w1; g1 -= CC_ * (dn1 * rsqrtf(fmaf(dn1, dn1, 1e-10f))); }
      v1 = fmaf(-LR_, g1, w1);
    }

    // ---- Michelot projection, warm-started from previous theta.
    //      Exit (ns==Ssum && nc==Cnt) certifies Sum max(v-theta,0) == 1 exactly;
    //      pass-7 reset to full support restores the monotone guarantee. ----
    float a1m = val1 ? 1.f : 0.f;
    float na0 = (v0 > thp) ? 1.f : 0.f;
    float na1 = (val1 && (v1 > thp)) ? 1.f : 0.f;
    float Ssum = wred64(na0 * v0 + na1 * v1);
    float Cnt  = wred64(na0 + na1);
    if (Cnt < 0.5f) { Ssum = wred64(v0 + a1m * v1); Cnt = 100.f; }
    float theta = (Ssum - 1.f) / Cnt;
    for (int it = 0; it < 112; ++it) {
      na0 = (v0 > theta) ? 1.f : 0.f;
      na1 = (val1 && (v1 > theta)) ? 1.f : 0.f;
      float ns = wred64(na0 * v0 + na1 * v1);
      float nc = wred64(na0 + na1);
      if (nc == Cnt && ns == Ssum) break;
      if (it == 7) {  // warm-start may cycle: fall back to full support (monotone)
        ns = wred64(v0 + a1m * v1);
        nc = 100.f;
      }
      Ssum = ns; Cnt = nc;
      theta = (Ssum - 1.f) / Cnt;
    }
    thp = theta;
    w0 = fmaxf(v0 - theta, 0.f);
    w1 = val1 ? fmaxf(v1 - theta, 0.f) : 0.f;

    // ---------- publish w(k+1): A wave only ----------
    if (sec == 0) {
      wbuf[(k + 1) & 3][j][lane] = w0;
      if (val1) wbuf[(k + 1) & 3][j][64 + lane] = w1;
      if (lane == 0)
        __hip_atomic_store(&wf[j], k + 1, __ATOMIC_RELEASE, __HIP_MEMORY_SCOPE_WORKGROUP);
      if (crossR || crossL) {
        float* dst = pbuf + ((size_t)flagPub * 4 + ((k + 1) & 3)) * 100;
        __hip_atomic_store(&dst[lane], w0, __ATOMIC_RELAXED, __HIP_MEMORY_SCOPE_AGENT);
        if (val1) __hip_atomic_store(&dst[64 + lane], w1, __ATOMIC_RELAXED, __HIP_MEMORY_SCOPE_AGENT);
        if (lane == 0)
          __hip_atomic_store(&flags[flagPub], k + 1, __ATOMIC_RELEASE, __HIP_MEMORY_SCOPE_AGENT);
      }
    }
  }

  if (sec == 0) {
    float* o = out + (size_t)bh * 100;
    o[lane] = w0;
    if (val1) o[64 + lane] = w1;
  }
}

extern "C" void kernel_launch(void* const* d_in, const int* in_sizes, int n_in,
                              void* d_out, int out_size, void* d_ws, size_t ws_size,
                              hipStream_t stream) {
  const float* mu = (const float*)d_in[0];
  const float* L  = (const float*)d_in[1];
  const float* wp = (const float*)d_in[2];
  const float* cl = (const float*)d_in[3];
  float* pbuf  = (float*)d_ws;
  int*   flags = (int*)((char*)d_ws + PBUF_BYTES);
  hipMemsetAsync(flags, 0, FLAG_COUNT * sizeof(int), stream);
  hipLaunchKernelGGL(mpo_solver, dim3(256), dim3(768), 0, stream,
                     mu, L, wp, cl, (float*)d_out, pbuf, flags);
}